// Round 4
// baseline (260.699 us; speedup 1.0000x reference)
//
#include <hip/hip_runtime.h>
#include <math.h>

#define B 32
#define L 2048
#define V 512
#define D 512
#define S_CTX 32     // pair-strided blocks per batch in the context kernel
#define CAP 512      // max unique masked positions per batch

// ws layout (bytes):
//   0      : int flag (1 = sparse_indices is int64)
//   256    : int wcnt[B]
//   1024   : float scores[B*L]   (256 KB)
//   +B*L*4 : int   clist[B*CAP]  (64 KB)
//   +...   : float cval[B*CAP]   (64 KB)

// scores = -inf, c = 0, and detect the index dtype (parallel, one ballot).
// int64 encoding: odd int32 words in [nnz, 2*nnz) are high halves of idx0
// (values < 32) == 0. int32 encoding: those words are idx1 values, random in
// [0, L) -> P(all 64 samples zero) = (1/2048)^64 ~ 0.
__global__ __launch_bounds__(256) void k_init(float* __restrict__ scores,
        float* __restrict__ c, const int* __restrict__ idx32, int nnz,
        int* __restrict__ flag) {
    int i = blockIdx.x * 256 + threadIdx.x;
    if (i < B * L) scores[i] = -INFINITY;
    if (i < B * D) c[i] = 0.f;
    if (blockIdx.x == 0 && threadIdx.x < 64) {
        int step = nnz / 128; if (step < 1) step = 1;
        int w = nnz + 1 + 2 * threadIdx.x * step;
        unsigned long long nz = __ballot(idx32[w] != 0);
        if (threadIdx.x == 0) *flag = (nz == 0ull) ? 1 : 0;
    }
}

// scores[b,l] = dot(bdi[b,l,:], W2). One wave per nnz entry.
// The reference also adds coef*(DHS@W1.T@W2)[b] — a per-batch constant over
// the masked set; softmax is shift-invariant and scores are not an output,
// so the entire W1/DHS path drops out exactly.
// Duplicate entries write identical values -> benign race.
__global__ __launch_bounds__(256) void k_scores(const float* __restrict__ bdi,
        const float* __restrict__ W2, const void* __restrict__ idx, int nnz,
        const int* __restrict__ flag, float* __restrict__ scores) {
    int wave = threadIdx.x >> 6, lane = threadIdx.x & 63;
    int e = blockIdx.x * 4 + wave;
    if (e >= nnz) return;
    int b, l;
    if (*flag) {
        const long long* q = (const long long*)idx;
        b = (int)q[e];
        l = (int)q[nnz + e];
    } else {
        const int* q = (const int*)idx;
        b = q[e];
        l = q[nnz + e];
    }
    const float4* row = (const float4*)(bdi + ((size_t)b * L + l) * V);
    const float4* w   = (const float4*)W2;
    float4 r0 = row[lane],      w0 = w[lane];
    float4 r1 = row[lane + 64], w1 = w[lane + 64];
    float acc = r0.x * w0.x + r0.y * w0.y + r0.z * w0.z + r0.w * w0.w
              + r1.x * w1.x + r1.y * w1.y + r1.z * w1.z + r1.w * w1.w;
    for (int off = 32; off; off >>= 1) acc += __shfl_down(acc, off, 64);
    if (lane == 0) scores[b * L + l] = acc;
}

// Per-batch masked softmax over L (off-pattern scores are -inf -> exp 0).
// Emits alpha [B,L] plus a compact (l, alpha) list per batch.
__global__ __launch_bounds__(256) void k_softmax(const float* __restrict__ scores,
        float* __restrict__ alpha, int* __restrict__ clist,
        float* __restrict__ cval, int* __restrict__ wcnt) {
    int b = blockIdx.x, tid = threadIdx.x;
    __shared__ float e_s[L];     // 8 KB
    __shared__ float red[256];
    __shared__ int cnt;
    if (tid == 0) cnt = 0;
    const float4* sv = (const float4*)(scores + b * L);
    float4 v0 = sv[tid], v1 = sv[tid + 256];
    ((float4*)e_s)[tid] = v0;
    ((float4*)e_s)[tid + 256] = v1;
    float m = fmaxf(fmaxf(fmaxf(v0.x, v0.y), fmaxf(v0.z, v0.w)),
                    fmaxf(fmaxf(v1.x, v1.y), fmaxf(v1.z, v1.w)));
    red[tid] = m;
    __syncthreads();
    for (int off = 128; off; off >>= 1) {
        if (tid < off) red[tid] = fmaxf(red[tid], red[tid + off]);
        __syncthreads();
    }
    m = red[0];
    __syncthreads();
    float sum = 0.f;
    for (int l = tid; l < L; l += 256) {
        float e = __expf(e_s[l] - m);   // exp(-inf - m) = 0 off-pattern
        e_s[l] = e;
        sum += e;
    }
    red[tid] = sum;
    __syncthreads();
    for (int off = 128; off; off >>= 1) {
        if (tid < off) red[tid] += red[tid + off];
        __syncthreads();
    }
    float inv = 1.f / red[0];
    __syncthreads();
    float4* av = (float4*)(alpha + b * L);
    #pragma unroll
    for (int seg = 0; seg < 2; ++seg) {
        int q = tid + seg * 256;            // float4 index into the row
        float4 e4 = ((const float4*)e_s)[q];
        float4 a4 = {e4.x * inv, e4.y * inv, e4.z * inv, e4.w * inv};
        av[q] = a4;
        float av_[4] = {a4.x, a4.y, a4.z, a4.w};
        #pragma unroll
        for (int k = 0; k < 4; ++k) {
            if (av_[k] > 0.f) {
                int p = atomicAdd(&cnt, 1);
                clist[b * CAP + p] = q * 4 + k;
                cval[b * CAP + p]  = av_[k];
            }
        }
    }
    __syncthreads();
    if (tid == 0) wcnt[b] = cnt;
}

// c[b,:] += sum over this block's stride of the compact list of att[b,l,:]*a.
// 256 threads = 2 halves x 128 float4 lanes: each iteration covers 2 rows.
__global__ __launch_bounds__(256) void k_context(const float* __restrict__ att,
        const int* __restrict__ clist, const float* __restrict__ cval,
        const int* __restrict__ wcnt, float* __restrict__ c) {
    int b = blockIdx.x / S_CTX, s = blockIdx.x % S_CTX;
    int n = wcnt[b];
    int half = threadIdx.x >> 7;   // 0/1: which row of the pair (wave-uniform)
    int dq   = threadIdx.x & 127;  // float4 index within the D=512 row
    float4 acc = {0.f, 0.f, 0.f, 0.f};
    for (int j0 = s * 2; j0 < n; j0 += S_CTX * 2) {
        int j = j0 + half;
        if (j < n) {
            int   l = clist[b * CAP + j];
            float a = cval[b * CAP + j];
            float4 v = *(const float4*)(att + ((size_t)b * L + l) * D + dq * 4);
            acc.x += a * v.x;
            acc.y += a * v.y;
            acc.z += a * v.z;
            acc.w += a * v.w;
        }
    }
    float* cb = c + b * D + dq * 4;
    atomicAdd(cb + 0, acc.x);
    atomicAdd(cb + 1, acc.y);
    atomicAdd(cb + 2, acc.z);
    atomicAdd(cb + 3, acc.w);
}

extern "C" void kernel_launch(void* const* d_in, const int* in_sizes, int n_in,
                              void* d_out, int out_size, void* d_ws, size_t ws_size,
                              hipStream_t stream) {
    const float* bdi  = (const float*)d_in[1];
    const float* att  = (const float*)d_in[2];
    const void*  sidx = d_in[3];
    const float* W2   = (const float*)d_in[6];

    float* out   = (float*)d_out;
    float* c     = out;            // [B, D]
    float* alpha = out + B * D;    // [B, L] (== [B,L,1])
    int nnz = in_sizes[3] / 2;     // element count is 2*nnz for int32 or int64

    char* ws = (char*)d_ws;
    int*   flag   = (int*)ws;
    int*   wcnt   = (int*)(ws + 256);
    float* scores = (float*)(ws + 1024);
    int*   clist  = (int*)(ws + 1024 + B * L * 4);
    float* cval   = (float*)(ws + 1024 + B * L * 4 + B * CAP * 4);

    k_init<<<(B * L + 255) / 256, 256, 0, stream>>>(scores, c, (const int*)sidx, nnz, flag);
    k_scores<<<(nnz + 3) / 4, 256, 0, stream>>>(bdi, W2, sidx, nnz, flag, scores);
    k_softmax<<<B, 256, 0, stream>>>(scores, alpha, clist, cval, wcnt);
    k_context<<<B * S_CTX, 256, 0, stream>>>(att, clist, cval, wcnt, c);
}